// Round 1
// baseline (632.771 us; speedup 1.0000x reference)
//
#include <hip/hip_runtime.h>
#include <cstdint>
#include <cstddef>

#define DM   512
#define SQL  4096
#define NHE  8
#define HDM  64
#define DFF  2048
#define NB   2

typedef unsigned short u16t;
typedef __attribute__((ext_vector_type(8))) __bf16 bf16x8;
typedef __attribute__((ext_vector_type(4))) float f32x4;
typedef __attribute__((ext_vector_type(8))) unsigned short us8;
typedef __attribute__((ext_vector_type(4))) unsigned short us4;

__device__ inline f32x4 mfma16(bf16x8 a, bf16x8 b, f32x4 c) {
    return __builtin_amdgcn_mfma_f32_16x16x32_bf16(a, b, c, 0, 0, 0);
}

// async global->LDS, 16B per lane; LDS dest = base + lane*16
__device__ inline void load_lds16(const void* g, void* l) {
    __builtin_amdgcn_global_load_lds(
        (const __attribute__((address_space(1))) unsigned int*)g,
        (__attribute__((address_space(3))) unsigned int*)l, 16, 0, 0);
}

__device__ inline u16t f2bf(float x) {
    union { float f; unsigned int u; } v; v.f = x;
    unsigned int r = v.u + 0x7fffu + ((v.u >> 16) & 1u);
    return (u16t)(r >> 16);
}

__device__ inline void store_out(float* C, size_t idx, float v) { C[idx] = v; }
__device__ inline void store_out(u16t* C, size_t idx, float v) { C[idx] = f2bf(v); }

// ---------------- fp32 -> bf16 convert ----------------
__global__ __launch_bounds__(256) void f32_to_bf16_k(const float* __restrict__ s,
                                                     u16t* __restrict__ d, const int n) {
    const int i = (blockIdx.x * 256 + threadIdx.x) * 8;
    if (i >= n) return;
    f32x4 a = *(const f32x4*)(s + i);
    f32x4 b = *(const f32x4*)(s + i + 4);
    us8 o;
    o[0] = f2bf(a[0]); o[1] = f2bf(a[1]); o[2] = f2bf(a[2]); o[3] = f2bf(a[3]);
    o[4] = f2bf(b[0]); o[5] = f2bf(b[1]); o[6] = f2bf(b[2]); o[7] = f2bf(b[3]);
    *(us8*)(d + i) = o;
}

// ---------------- mask all-ones check ----------------
__global__ void init_flag_k(int* flag) { if (threadIdx.x == 0) flag[0] = 1; }

__global__ __launch_bounds__(256) void check_mask_k(const f32x4* __restrict__ m, int* flag) {
    const size_t n4 = (size_t)NB * SQL * SQL / 4;
    size_t i = (size_t)blockIdx.x * 256 + threadIdx.x;
    bool bad = false;
    for (; i < n4; i += (size_t)gridDim.x * 256) {
        f32x4 v = m[i];
        bad |= (v[0] != 1.0f) || (v[1] != 1.0f) || (v[2] != 1.0f) || (v[3] != 1.0f);
    }
    if (bad) flag[0] = 0;
}

// ---------------- GEMM: C[M,N] = A[M,K] @ B[N,K]^T + bias, bf16 in, f32 acc --------
// m97 structure: 128x128 tile, BK=32, 4 waves as 2x2, each wave 64x64 (4x4 MFMA tiles)
template <typename OutT, bool RELU>
__global__ __launch_bounds__(256, 3) void gemm_bt(const u16t* __restrict__ A,
                                                  const u16t* __restrict__ Bw,
                                                  const float* __restrict__ bias,
                                                  OutT* __restrict__ C,
                                                  const int M, const int N, const int K,
                                                  const int ldc) {
    __shared__ u16t As[128 * 32];
    __shared__ u16t Bs[128 * 32];
    const int tid = threadIdx.x;
    const int w = tid >> 6, lane = tid & 63;
    const int l15 = lane & 15, quad = lane >> 4;
    const int m0 = blockIdx.y * 128, n0 = blockIdx.x * 128;
    const int wm = w >> 1, wn = w & 1;

    f32x4 acc[4][4] = {};

    const u16t* Ag = A + ((size_t)(m0 + w * 32 + (lane >> 2))) * K + (lane & 3) * 8;
    const u16t* Bg = Bw + ((size_t)(n0 + w * 32 + (lane >> 2))) * K + (lane & 3) * 8;
    u16t* Asw = &As[(w * 32) * 32];
    u16t* Bsw = &Bs[(w * 32) * 32];

    for (int k0 = 0; k0 < K; k0 += 32) {
        __syncthreads();
        load_lds16(Ag + k0, Asw);
        load_lds16(Ag + (size_t)16 * K + k0, Asw + 16 * 32);
        load_lds16(Bg + k0, Bsw);
        load_lds16(Bg + (size_t)16 * K + k0, Bsw + 16 * 32);
        __syncthreads();
        bf16x8 af[4], bfr[4];
#pragma unroll
        for (int mt = 0; mt < 4; ++mt)
            af[mt] = *(const bf16x8*)&As[(wm * 64 + mt * 16 + l15) * 32 + quad * 8];
#pragma unroll
        for (int nt = 0; nt < 4; ++nt)
            bfr[nt] = *(const bf16x8*)&Bs[(wn * 64 + nt * 16 + l15) * 32 + quad * 8];
#pragma unroll
        for (int mt = 0; mt < 4; ++mt)
#pragma unroll
            for (int nt = 0; nt < 4; ++nt)
                acc[mt][nt] = mfma16(af[mt], bfr[nt], acc[mt][nt]);
    }

    float bv[4];
#pragma unroll
    for (int nt = 0; nt < 4; ++nt) bv[nt] = bias[n0 + wn * 64 + nt * 16 + l15];
#pragma unroll
    for (int mt = 0; mt < 4; ++mt)
#pragma unroll
        for (int r = 0; r < 4; ++r) {
            const int row = m0 + wm * 64 + mt * 16 + quad * 4 + r;
#pragma unroll
            for (int nt = 0; nt < 4; ++nt) {
                float v = acc[mt][nt][r] + bv[nt];
                if (RELU) v = fmaxf(v, 0.0f);
                store_out(C, (size_t)row * ldc + n0 + wn * 64 + nt * 16 + l15, v);
            }
        }
}

// ---------------- V transpose: qkv[b,s,1024+h*64+d] -> vt[(b*8+h)*64+d][s] ----------
__global__ __launch_bounds__(256) void transpose_v(const u16t* __restrict__ qkv,
                                                   u16t* __restrict__ vt) {
    __shared__ u16t t[64 * 72];
    const int sb = blockIdx.x, h = blockIdx.y, b = blockIdx.z;
    const int tid = threadIdx.x;
#pragma unroll
    for (int it = 0; it < 2; ++it) {
        const int idx = it * 256 + tid;
        const int r = idx >> 3, c8 = idx & 7;
        const u16t* gp = qkv + (size_t)(b * SQL + sb * 64 + r) * (3 * DM) + 2 * DM + h * HDM + c8 * 8;
        *(us8*)&t[r * 72 + c8 * 8] = *(const us8*)gp;
    }
    __syncthreads();
#pragma unroll
    for (int it = 0; it < 2; ++it) {
        const int idx = it * 256 + tid;
        const int d = idx >> 3, s8 = idx & 7;
        us8 o;
#pragma unroll
        for (int u = 0; u < 8; ++u) o[u] = t[(s8 * 8 + u) * 72 + d];
        u16t* gp = vt + (size_t)((b * NHE + h) * HDM + d) * SQL + sb * 64 + s8 * 8;
        *(us8*)gp = o;
    }
}

// ---------------- flash attention ----------------
// block = (qt, h, b); 128 Q-rows; K-tile 128x64, V-tile (transposed) 64x128; 4 waves,
// each wave owns 32 Q-rows. Online softmax state in C-layout registers.
__global__ __launch_bounds__(256, 2) void flash_attn(const u16t* __restrict__ qkv,
                                                     const u16t* __restrict__ vtg,
                                                     const float* __restrict__ mask,
                                                     const int* __restrict__ flag,
                                                     u16t* __restrict__ ctx) {
    __shared__ u16t Ks[128 * 64];
    __shared__ u16t Vs[64 * 128];
    __shared__ u16t Ps[4][32 * 128];

    const int qt = blockIdx.x, h = blockIdx.y, b = blockIdx.z;
    const int tid = threadIdx.x;
    const int w = tid >> 6, lane = tid & 63;
    const int l15 = lane & 15, quad = lane >> 4;
    const bool allones = (*flag != 0);

    // Q fragments in registers (A-operand layout: m=lane&15, k=quad*8+j)
    bf16x8 qf[2][2];
#pragma unroll
    for (int mt = 0; mt < 2; ++mt) {
        const size_t rowb = (size_t)(b * SQL + qt * 128 + w * 32 + mt * 16 + l15) * (3 * DM) + h * HDM;
#pragma unroll
        for (int kk = 0; kk < 2; ++kk)
            qf[mt][kk] = *(const bf16x8*)(qkv + rowb + kk * 32 + quad * 8);
    }

    f32x4 oacc[2][4] = {};
    float m_r[2][4], l_r[2][4];
#pragma unroll
    for (int mt = 0; mt < 2; ++mt)
#pragma unroll
        for (int r = 0; r < 4; ++r) { m_r[mt][r] = -3.0e38f; l_r[mt][r] = 0.0f; }

    for (int kt = 0; kt < SQL / 128; ++kt) {
        const int j0 = kt * 128;
        __syncthreads();
#pragma unroll
        for (int i = 0; i < 4; ++i) {  // K-tile: rows w*32+i*8 .. +8
            const int r = w * 32 + i * 8 + (lane >> 3);
            load_lds16(qkv + (size_t)(b * SQL + j0 + r) * (3 * DM) + DM + h * HDM + (lane & 7) * 8,
                       &Ks[(w * 32 + i * 8) * 64]);
        }
#pragma unroll
        for (int i = 0; i < 4; ++i) {  // V^T tile: d-rows w*16+i*4 .. +4
            const int d = w * 16 + i * 4 + (lane >> 4);
            load_lds16(vtg + (size_t)((b * NHE + h) * HDM + d) * SQL + j0 + (lane & 15) * 8,
                       &Vs[(w * 16 + i * 4) * 128]);
        }
        __syncthreads();

        // S = Q K^T  (wave rows w*32..w*32+31, all 128 cols)
        f32x4 sacc[2][8] = {};
#pragma unroll
        for (int kk = 0; kk < 2; ++kk) {
            bf16x8 a0 = qf[0][kk], a1 = qf[1][kk];
#pragma unroll
            for (int nt = 0; nt < 8; ++nt) {
                bf16x8 bb = *(const bf16x8*)&Ks[(nt * 16 + l15) * 64 + kk * 32 + quad * 8];
                sacc[0][nt] = mfma16(a0, bb, sacc[0][nt]);
                sacc[1][nt] = mfma16(a1, bb, sacc[1][nt]);
            }
        }

        // online softmax (C-layout: row = quad*4+r within 16-tile, col = l15)
#pragma unroll
        for (int mt = 0; mt < 2; ++mt) {
#pragma unroll
            for (int r = 0; r < 4; ++r) {
                float mx = -3.0e38f;
#pragma unroll
                for (int nt = 0; nt < 8; ++nt) {
                    float v = sacc[mt][nt][r] * 0.125f;
                    if (!allones) {
                        const int gi = qt * 128 + w * 32 + mt * 16 + quad * 4 + r;
                        const int gj = j0 + nt * 16 + l15;
                        v += (1.0f - mask[((size_t)b * SQL + gi) * SQL + gj]) * (-1.0e9f);
                    }
                    sacc[mt][nt][r] = v;
                    mx = fmaxf(mx, v);
                }
                mx = fmaxf(mx, __shfl_xor(mx, 1));
                mx = fmaxf(mx, __shfl_xor(mx, 2));
                mx = fmaxf(mx, __shfl_xor(mx, 4));
                mx = fmaxf(mx, __shfl_xor(mx, 8));
                const float mnew = fmaxf(m_r[mt][r], mx);
                const float alpha = __expf(m_r[mt][r] - mnew);
                m_r[mt][r] = mnew;
                float rsum = 0.0f;
#pragma unroll
                for (int nt = 0; nt < 8; ++nt) {
                    const float p = __expf(sacc[mt][nt][r] - mnew);
                    sacc[mt][nt][r] = p;
                    rsum += p;
                }
                rsum += __shfl_xor(rsum, 1);
                rsum += __shfl_xor(rsum, 2);
                rsum += __shfl_xor(rsum, 4);
                rsum += __shfl_xor(rsum, 8);
                l_r[mt][r] = l_r[mt][r] * alpha + rsum;
#pragma unroll
                for (int nt = 0; nt < 4; ++nt) oacc[mt][nt][r] *= alpha;
                // P -> wave-private LDS (bf16), row m, col j
#pragma unroll
                for (int nt = 0; nt < 8; ++nt)
                    Ps[w][(mt * 16 + quad * 4 + r) * 128 + nt * 16 + l15] = f2bf(sacc[mt][nt][r]);
            }
        }

        // O += P @ V   (A = P from LDS, B = V^T tile, contiguous-K reads)
#pragma unroll
        for (int ks = 0; ks < 4; ++ks) {
            bf16x8 a0 = *(const bf16x8*)&Ps[w][(l15) * 128 + ks * 32 + quad * 8];
            bf16x8 a1 = *(const bf16x8*)&Ps[w][(16 + l15) * 128 + ks * 32 + quad * 8];
#pragma unroll
            for (int nt = 0; nt < 4; ++nt) {
                bf16x8 bb = *(const bf16x8*)&Vs[(nt * 16 + l15) * 128 + ks * 32 + quad * 8];
                oacc[0][nt] = mfma16(a0, bb, oacc[0][nt]);
                oacc[1][nt] = mfma16(a1, bb, oacc[1][nt]);
            }
        }
    }

#pragma unroll
    for (int mt = 0; mt < 2; ++mt)
#pragma unroll
        for (int r = 0; r < 4; ++r) {
            const float inv = 1.0f / l_r[mt][r];
            const int gi = qt * 128 + w * 32 + mt * 16 + quad * 4 + r;
            const size_t base = ((size_t)b * SQL + gi) * DM + h * HDM;
#pragma unroll
            for (int nt = 0; nt < 4; ++nt)
                ctx[base + nt * 16 + l15] = f2bf(oacc[mt][nt][r] * inv);
        }
}

// ---------------- fused residual + LayerNorm (one wave per 512-elem row) -----------
template <bool WBF>
__global__ __launch_bounds__(256) void ln_fused(const float* __restrict__ xa,
                                                const float* __restrict__ xb,
                                                const float* __restrict__ g,
                                                const float* __restrict__ be,
                                                float* __restrict__ outf,
                                                u16t* __restrict__ outh) {
    const int row = blockIdx.x * 4 + (threadIdx.x >> 6);
    const int lane = threadIdx.x & 63;
    const size_t base = (size_t)row * DM;
    f32x4 a0 = *(const f32x4*)(xa + base + lane * 4);
    f32x4 b0 = *(const f32x4*)(xb + base + lane * 4);
    f32x4 a1 = *(const f32x4*)(xa + base + 256 + lane * 4);
    f32x4 b1 = *(const f32x4*)(xb + base + 256 + lane * 4);
    f32x4 v0 = a0 + b0, v1 = a1 + b1;
    float s = v0[0] + v0[1] + v0[2] + v0[3] + v1[0] + v1[1] + v1[2] + v1[3];
    float q = v0[0]*v0[0] + v0[1]*v0[1] + v0[2]*v0[2] + v0[3]*v0[3]
            + v1[0]*v1[0] + v1[1]*v1[1] + v1[2]*v1[2] + v1[3]*v1[3];
#pragma unroll
    for (int off = 1; off < 64; off <<= 1) {
        s += __shfl_xor(s, off);
        q += __shfl_xor(q, off);
    }
    const float mean = s * (1.0f / DM);
    const float var = q * (1.0f / DM) - mean * mean;
    const float rs = rsqrtf(var + 1e-5f);
    f32x4 g0 = *(const f32x4*)(g + lane * 4);
    f32x4 g1 = *(const f32x4*)(g + 256 + lane * 4);
    f32x4 e0 = *(const f32x4*)(be + lane * 4);
    f32x4 e1 = *(const f32x4*)(be + 256 + lane * 4);
    f32x4 y0, y1;
#pragma unroll
    for (int i = 0; i < 4; ++i) {
        y0[i] = (v0[i] - mean) * rs * g0[i] + e0[i];
        y1[i] = (v1[i] - mean) * rs * g1[i] + e1[i];
    }
    *(f32x4*)(outf + base + lane * 4) = y0;
    *(f32x4*)(outf + base + 256 + lane * 4) = y1;
    if (WBF) {
        us4 h0, h1;
#pragma unroll
        for (int i = 0; i < 4; ++i) { h0[i] = f2bf(y0[i]); h1[i] = f2bf(y1[i]); }
        *(us4*)(outh + base + lane * 4) = h0;
        *(us4*)(outh + base + 256 + lane * 4) = h1;
    }
}

// ---------------- host ----------------
extern "C" void kernel_launch(void* const* d_in, const int* in_sizes, int n_in,
                              void* d_out, int out_size, void* d_ws, size_t ws_size,
                              hipStream_t stream) {
    const float* src  = (const float*)d_in[0];
    const float* mask = (const float*)d_in[1];
    const float* Wq = (const float*)d_in[2];
    const float* bq = (const float*)d_in[3];
    const float* Wk = (const float*)d_in[4];
    const float* bk = (const float*)d_in[5];
    const float* Wv = (const float*)d_in[6];
    const float* bv = (const float*)d_in[7];
    const float* Wo = (const float*)d_in[8];
    const float* bo = (const float*)d_in[9];
    const float* W1 = (const float*)d_in[10];
    const float* b1 = (const float*)d_in[11];
    const float* W2 = (const float*)d_in[12];
    const float* b2 = (const float*)d_in[13];
    const float* ln1g = (const float*)d_in[14];
    const float* ln1b = (const float*)d_in[15];
    const float* ln2g = (const float*)d_in[16];
    const float* ln2b = (const float*)d_in[17];

    const int M = NB * SQL;  // 8192 tokens

    char* p = (char*)d_ws;
    auto take = [&](size_t bytes) {
        char* r = p;
        p += (bytes + 1023) & ~(size_t)1023;
        return r;
    };
    u16t* regA   = (u16t*)take((size_t)M * DFF * 2);      // qkv [M,1536] then h [M,2048]
    u16t* vtb    = (u16t*)take((size_t)NB * NHE * HDM * SQL * 2);
    u16t* ctxb   = (u16t*)take((size_t)M * DM * 2);
    float* sa_ff = (float*)take((size_t)M * DM * 4);      // sa then ff
    float* x1f   = (float*)take((size_t)M * DM * 4);
    u16t* x1h    = (u16t*)take((size_t)M * DM * 2);
    u16t* srcbf  = (u16t*)take((size_t)M * DM * 2);
    u16t* wqkv   = (u16t*)take((size_t)3 * DM * DM * 2);
    float* bqkv  = (float*)take((size_t)3 * DM * 4);
    u16t* woc    = (u16t*)take((size_t)DM * DM * 2);
    u16t* w1c    = (u16t*)take((size_t)DFF * DM * 2);
    u16t* w2c    = (u16t*)take((size_t)DM * DFF * 2);
    int* flag    = (int*)take(1024);
    u16t* qkvb   = regA;   // [M, 1536]
    u16t* hbuf   = regA;   // [M, 2048] (after flash is done with qkv)

    // converts
    f32_to_bf16_k<<<(M * DM) / 2048, 256, 0, stream>>>(src, srcbf, M * DM);
    f32_to_bf16_k<<<(DM * DM) / 2048, 256, 0, stream>>>(Wq, wqkv, DM * DM);
    f32_to_bf16_k<<<(DM * DM) / 2048, 256, 0, stream>>>(Wk, wqkv + DM * DM, DM * DM);
    f32_to_bf16_k<<<(DM * DM) / 2048, 256, 0, stream>>>(Wv, wqkv + 2 * DM * DM, DM * DM);
    f32_to_bf16_k<<<(DM * DM) / 2048, 256, 0, stream>>>(Wo, woc, DM * DM);
    f32_to_bf16_k<<<(DFF * DM) / 2048, 256, 0, stream>>>(W1, w1c, DFF * DM);
    f32_to_bf16_k<<<(DM * DFF) / 2048, 256, 0, stream>>>(W2, w2c, DM * DFF);
    hipMemcpyAsync(bqkv, bq, DM * 4, hipMemcpyDeviceToDevice, stream);
    hipMemcpyAsync(bqkv + DM, bk, DM * 4, hipMemcpyDeviceToDevice, stream);
    hipMemcpyAsync(bqkv + 2 * DM, bv, DM * 4, hipMemcpyDeviceToDevice, stream);

    // mask all-ones check
    init_flag_k<<<1, 64, 0, stream>>>(flag);
    check_mask_k<<<4096, 256, 0, stream>>>((const f32x4*)mask, flag);

    // QKV projection: [8192,512] x [1536,512]^T -> [8192,1536] bf16
    gemm_bt<u16t, false><<<dim3(12, 64), 256, 0, stream>>>(srcbf, wqkv, bqkv, qkvb,
                                                           M, 3 * DM, DM, 3 * DM);
    // V transpose for flash B-operand
    transpose_v<<<dim3(SQL / 64, NHE, NB), 256, 0, stream>>>(qkvb, vtb);
    // attention
    flash_attn<<<dim3(SQL / 128, NHE, NB), 256, 0, stream>>>(qkvb, vtb, mask, flag, ctxb);
    // out projection -> sa (fp32)
    gemm_bt<float, false><<<dim3(4, 64), 256, 0, stream>>>(ctxb, woc, bo, sa_ff,
                                                           M, DM, DM, DM);
    // x1 = LN(src + sa)  (fp32 + bf16 copies)
    ln_fused<true><<<M / 4, 256, 0, stream>>>(src, sa_ff, ln1g, ln1b, x1f, x1h);
    // FFN1 + ReLU -> h (bf16)
    gemm_bt<u16t, true><<<dim3(16, 64), 256, 0, stream>>>(x1h, w1c, b1, hbuf,
                                                          M, DFF, DM, DFF);
    // FFN2 -> ff (fp32, reuses sa buffer)
    gemm_bt<float, false><<<dim3(4, 64), 256, 0, stream>>>(hbuf, w2c, b2, sa_ff,
                                                           M, DM, DFF, DM);
    // out = LN(x1 + ff)
    ln_fused<false><<<M / 4, 256, 0, stream>>>(x1f, sa_ff, ln2g, ln2b, (float*)d_out,
                                               (u16t*)nullptr);
}

// Round 2
// 497.160 us; speedup vs baseline: 1.2728x; 1.2728x over previous
//
#include <hip/hip_runtime.h>
#include <cstdint>
#include <cstddef>

#define DM   512
#define SQL  4096
#define NHE  8
#define HDM  64
#define DFF  2048
#define NB   2

typedef unsigned short u16t;
typedef __attribute__((ext_vector_type(8))) __bf16 bf16x8;
typedef __attribute__((ext_vector_type(4))) float f32x4;
typedef __attribute__((ext_vector_type(8))) unsigned short us8;
typedef __attribute__((ext_vector_type(4))) unsigned short us4;

__device__ inline f32x4 mfma16(bf16x8 a, bf16x8 b, f32x4 c) {
    return __builtin_amdgcn_mfma_f32_16x16x32_bf16(a, b, c, 0, 0, 0);
}

// async global->LDS, 16B per lane; LDS dest = wave-uniform base + lane*16
__device__ inline void load_lds16(const void* g, void* l) {
    __builtin_amdgcn_global_load_lds(
        (const __attribute__((address_space(1))) unsigned int*)g,
        (__attribute__((address_space(3))) unsigned int*)l, 16, 0, 0);
}

__device__ inline u16t f2bf(float x) {
    union { float f; unsigned int u; } v; v.f = x;
    unsigned int r = v.u + 0x7fffu + ((v.u >> 16) & 1u);
    return (u16t)(r >> 16);
}

__device__ inline void store_out(float* C, size_t idx, float v) { C[idx] = v; }
__device__ inline void store_out(u16t* C, size_t idx, float v) { C[idx] = f2bf(v); }

// ---------------- merged fp32->bf16 converts + bias pack + flag init ----------------
__global__ __launch_bounds__(256) void convert_all(
    const float* __restrict__ src, const float* __restrict__ Wq,
    const float* __restrict__ Wk, const float* __restrict__ Wv,
    const float* __restrict__ Wo, const float* __restrict__ W1,
    const float* __restrict__ W2, const float* __restrict__ bq,
    const float* __restrict__ bk, const float* __restrict__ bv,
    u16t* __restrict__ srcbf, u16t* __restrict__ wqkv, u16t* __restrict__ woc,
    u16t* __restrict__ w1c, u16t* __restrict__ w2c,
    float* __restrict__ bqkv, int* __restrict__ flag) {
    const int blk = blockIdx.x;
    const float* s;
    u16t* d;
    int base;
    if (blk < 2048)      { s = src; d = srcbf;           base = blk; }
    else if (blk < 2176) { s = Wq;  d = wqkv;            base = blk - 2048; }
    else if (blk < 2304) { s = Wk;  d = wqkv + 262144;   base = blk - 2176; }
    else if (blk < 2432) { s = Wv;  d = wqkv + 524288;   base = blk - 2304; }
    else if (blk < 2560) { s = Wo;  d = woc;             base = blk - 2432; }
    else if (blk < 3072) { s = W1;  d = w1c;             base = blk - 2560; }
    else if (blk < 3584) { s = W2;  d = w2c;             base = blk - 3072; }
    else {
        for (int i = threadIdx.x; i < 1536; i += 256)
            bqkv[i] = (i < 512) ? bq[i] : (i < 1024 ? bk[i - 512] : bv[i - 1024]);
        if (threadIdx.x == 0) flag[0] = 1;
        return;
    }
    const int i = base * 2048 + threadIdx.x * 8;
    f32x4 a = *(const f32x4*)(s + i);
    f32x4 b = *(const f32x4*)(s + i + 4);
    us8 o;
    o[0] = f2bf(a[0]); o[1] = f2bf(a[1]); o[2] = f2bf(a[2]); o[3] = f2bf(a[3]);
    o[4] = f2bf(b[0]); o[5] = f2bf(b[1]); o[6] = f2bf(b[2]); o[7] = f2bf(b[3]);
    *(us8*)(d + i) = o;
}

// ---------------- mask all-ones check ----------------
__global__ __launch_bounds__(256) void check_mask_k(const f32x4* __restrict__ m, int* flag) {
    const size_t n4 = (size_t)NB * SQL * SQL / 4;
    size_t i = (size_t)blockIdx.x * 256 + threadIdx.x;
    bool bad = false;
    for (; i < n4; i += (size_t)gridDim.x * 256) {
        f32x4 v = m[i];
        bad |= (v[0] != 1.0f) || (v[1] != 1.0f) || (v[2] != 1.0f) || (v[3] != 1.0f);
    }
    if (bad) flag[0] = 0;
}

// ---------------- GEMM: C[M,N] = A[M,K] @ B[N,K]^T + bias, bf16 in, f32 acc --------
template <typename OutT, bool RELU>
__global__ __launch_bounds__(256, 3) void gemm_bt(const u16t* __restrict__ A,
                                                  const u16t* __restrict__ Bw,
                                                  const float* __restrict__ bias,
                                                  OutT* __restrict__ C,
                                                  const int M, const int N, const int K,
                                                  const int ldc) {
    __shared__ u16t As[128 * 32];
    __shared__ u16t Bs[128 * 32];
    const int tid = threadIdx.x;
    const int w = tid >> 6, lane = tid & 63;
    const int l15 = lane & 15, quad = lane >> 4;
    const int m0 = blockIdx.y * 128, n0 = blockIdx.x * 128;
    const int wm = w >> 1, wn = w & 1;

    f32x4 acc[4][4] = {};

    const u16t* Ag = A + ((size_t)(m0 + w * 32 + (lane >> 2))) * K + (lane & 3) * 8;
    const u16t* Bg = Bw + ((size_t)(n0 + w * 32 + (lane >> 2))) * K + (lane & 3) * 8;
    u16t* Asw = &As[(w * 32) * 32];
    u16t* Bsw = &Bs[(w * 32) * 32];

    for (int k0 = 0; k0 < K; k0 += 32) {
        __syncthreads();
        load_lds16(Ag + k0, Asw);
        load_lds16(Ag + (size_t)16 * K + k0, Asw + 16 * 32);
        load_lds16(Bg + k0, Bsw);
        load_lds16(Bg + (size_t)16 * K + k0, Bsw + 16 * 32);
        __syncthreads();
        bf16x8 af[4], bfr[4];
#pragma unroll
        for (int mt = 0; mt < 4; ++mt)
            af[mt] = *(const bf16x8*)&As[(wm * 64 + mt * 16 + l15) * 32 + quad * 8];
#pragma unroll
        for (int nt = 0; nt < 4; ++nt)
            bfr[nt] = *(const bf16x8*)&Bs[(wn * 64 + nt * 16 + l15) * 32 + quad * 8];
#pragma unroll
        for (int mt = 0; mt < 4; ++mt)
#pragma unroll
            for (int nt = 0; nt < 4; ++nt)
                acc[mt][nt] = mfma16(af[mt], bfr[nt], acc[mt][nt]);
    }

    float bv[4];
#pragma unroll
    for (int nt = 0; nt < 4; ++nt) bv[nt] = bias[n0 + wn * 64 + nt * 16 + l15];
#pragma unroll
    for (int mt = 0; mt < 4; ++mt)
#pragma unroll
        for (int r = 0; r < 4; ++r) {
            const int row = m0 + wm * 64 + mt * 16 + quad * 4 + r;
#pragma unroll
            for (int nt = 0; nt < 4; ++nt) {
                float v = acc[mt][nt][r] + bv[nt];
                if (RELU) v = fmaxf(v, 0.0f);
                store_out(C, (size_t)row * ldc + n0 + wn * 64 + nt * 16 + l15, v);
            }
        }
}

// ---------------- V transpose: qkv[b,s,1024+h*64+d] -> vt[(b*8+h)*64+d][s] ----------
__global__ __launch_bounds__(256) void transpose_v(const u16t* __restrict__ qkv,
                                                   u16t* __restrict__ vt) {
    __shared__ u16t t[64 * 72];
    const int sb = blockIdx.x, h = blockIdx.y, b = blockIdx.z;
    const int tid = threadIdx.x;
#pragma unroll
    for (int it = 0; it < 2; ++it) {
        const int idx = it * 256 + tid;
        const int r = idx >> 3, c8 = idx & 7;
        const u16t* gp = qkv + (size_t)(b * SQL + sb * 64 + r) * (3 * DM) + 2 * DM + h * HDM + c8 * 8;
        *(us8*)&t[r * 72 + c8 * 8] = *(const us8*)gp;
    }
    __syncthreads();
#pragma unroll
    for (int it = 0; it < 2; ++it) {
        const int idx = it * 256 + tid;
        const int d = idx >> 3, s8 = idx & 7;
        us8 o;
#pragma unroll
        for (int u = 0; u < 8; ++u) o[u] = t[(s8 * 8 + u) * 72 + d];
        u16t* gp = vt + (size_t)((b * NHE + h) * HDM + d) * SQL + sb * 64 + s8 * 8;
        *(us8*)gp = o;
    }
}

// ---------------- flash attention, S^T formulation, XOR-swizzled LDS ----------------
// S^T = K.Q^T  (lane holds 32 scores of ONE token: col m = lane&15)
// O^T = V^T.P^T (P^T packed to LDS with b64 writes; all LDS b128 reads conflict-free)
// Swizzle: logical 16B chunk c of row r lives at physical chunk c ^ (r & 7).
__global__ __launch_bounds__(256, 2) void flash_attn(const u16t* __restrict__ qkv,
                                                     const u16t* __restrict__ vtg,
                                                     const float* __restrict__ mask,
                                                     const int* __restrict__ flag,
                                                     u16t* __restrict__ ctx) {
    __shared__ u16t Ks[128 * 64];        // K[j][d], 8 chunks/row, swizzled
    __shared__ u16t Vs[64 * 128];        // V^T[d][j], 16 chunks/row, swizzled
    __shared__ u16t Ps[4][32 * 128];     // per-wave P^T as [m][j], 16 chunks/row, swizzled

    const int qt = blockIdx.x, h = blockIdx.y, b = blockIdx.z;
    const int tid = threadIdx.x;
    const int w = tid >> 6, lane = tid & 63;
    const int l15 = lane & 15, quad = lane >> 4;
    const int e3 = l15 & 7;
    const bool allones = (*flag != 0);

    // Q fragments (B-operand: n = token = l15, k = quad*8+j), register-resident
    bf16x8 qf[2][2];
#pragma unroll
    for (int mt = 0; mt < 2; ++mt) {
        const size_t rowb = (size_t)(b * SQL + qt * 128 + w * 32 + mt * 16 + l15) * (3 * DM) + h * HDM;
#pragma unroll
        for (int kk = 0; kk < 2; ++kk)
            qf[mt][kk] = *(const bf16x8*)(qkv + rowb + kk * 32 + quad * 8);
    }

    f32x4 oacc[4][2] = {};               // [dt][mt], O^T C-layout (col = token)
    float m_r[2] = {-3.0e38f, -3.0e38f};
    float l_r[2] = {0.0f, 0.0f};

    const int r8 = lane >> 3, c8 = lane & 7;     // K staging decomposition
    const int r4 = lane >> 4, c16 = lane & 15;   // V staging decomposition

    for (int kt = 0; kt < SQL / 128; ++kt) {
        const int j0 = kt * 128;
        __syncthreads();
        // K-tile staging: 4 x (8 rows x 8 chunks); source chunk swizzled so that
        // physical chunk ch of row holds logical chunk ch ^ (row & 7)
#pragma unroll
        for (int i = 0; i < 4; ++i) {
            const int row = j0 + w * 32 + i * 8 + r8;
            load_lds16(qkv + (size_t)(b * SQL + row) * (3 * DM) + DM + h * HDM + ((c8 ^ r8) * 8),
                       &Ks[(w * 32 + i * 8) * 64]);
        }
        // V^T-tile staging: 4 x (4 d-rows x 16 chunks)
#pragma unroll
        for (int i = 0; i < 4; ++i) {
            const int d = w * 16 + i * 4 + r4;
            load_lds16(vtg + (size_t)((b * NHE + h) * HDM + d) * SQL + j0 + ((c16 ^ ((i * 4 + r4) & 7)) * 8),
                       &Vs[(w * 16 + i * 4) * 128]);
        }
        __syncthreads();

        // S^T = K . Q^T : A = K-rows (m-dim = j), B = Q (n-dim = token)
        f32x4 sacc[2][8] = {};           // [mt][jt]; row = quad*4+r -> j, col = l15 -> m
#pragma unroll
        for (int kk = 0; kk < 2; ++kk) {
#pragma unroll
            for (int jt = 0; jt < 8; ++jt) {
                bf16x8 af = *(const bf16x8*)&Ks[(jt * 16 + l15) * 64 + (((kk * 4 + quad) ^ e3) * 8)];
                sacc[0][jt] = mfma16(af, qf[0][kk], sacc[0][jt]);
                sacc[1][jt] = mfma16(af, qf[1][kk], sacc[1][jt]);
            }
        }

        // online softmax: each lane owns full j-slice of one token per mt
#pragma unroll
        for (int mt = 0; mt < 2; ++mt) {
            float mx = -3.0e38f;
            if (allones) {
#pragma unroll
                for (int jt = 0; jt < 8; ++jt)
#pragma unroll
                    for (int r = 0; r < 4; ++r) {
                        const float v = sacc[mt][jt][r] * 0.125f;
                        sacc[mt][jt][r] = v;
                        mx = fmaxf(mx, v);
                    }
            } else {
                const int gi = qt * 128 + w * 32 + mt * 16 + l15;
#pragma unroll
                for (int jt = 0; jt < 8; ++jt)
#pragma unroll
                    for (int r = 0; r < 4; ++r) {
                        const int gj = j0 + jt * 16 + quad * 4 + r;
                        const float v = sacc[mt][jt][r] * 0.125f
                                      + (1.0f - mask[((size_t)b * SQL + gi) * SQL + gj]) * (-1.0e9f);
                        sacc[mt][jt][r] = v;
                        mx = fmaxf(mx, v);
                    }
            }
            mx = fmaxf(mx, __shfl_xor(mx, 16));
            mx = fmaxf(mx, __shfl_xor(mx, 32));
            const float mnew = fmaxf(m_r[mt], mx);
            const float alpha = __expf(m_r[mt] - mnew);
            m_r[mt] = mnew;
            float rsum = 0.0f;
#pragma unroll
            for (int jt = 0; jt < 8; ++jt) {
                us4 pk;
#pragma unroll
                for (int r = 0; r < 4; ++r) {
                    const float p = __expf(sacc[mt][jt][r] - mnew);
                    rsum += p;
                    pk[r] = f2bf(p);
                }
                // P^T[m][j]: m = mt*16+l15, j = jt*16 + quad*4 (+r packed)
                *(us4*)&Ps[w][(mt * 16 + l15) * 128
                              + (((jt * 2 + (quad >> 1)) ^ e3) * 8) + (quad & 1) * 4] = pk;
            }
            rsum += __shfl_xor(rsum, 16);
            rsum += __shfl_xor(rsum, 32);
            l_r[mt] = l_r[mt] * alpha + rsum;
#pragma unroll
            for (int dt = 0; dt < 4; ++dt)
#pragma unroll
                for (int r = 0; r < 4; ++r) oacc[dt][mt][r] *= alpha;
        }

        // O^T += V^T . P^T : A = V^T (m-dim = d), B = P^T (n-dim = token)
#pragma unroll
        for (int ks = 0; ks < 4; ++ks) {
            const int pc = ((ks * 4 + quad) ^ e3) * 8;
            bf16x8 pb0 = *(const bf16x8*)&Ps[w][(l15) * 128 + pc];
            bf16x8 pb1 = *(const bf16x8*)&Ps[w][(16 + l15) * 128 + pc];
#pragma unroll
            for (int dt = 0; dt < 4; ++dt) {
                bf16x8 av = *(const bf16x8*)&Vs[(dt * 16 + l15) * 128 + pc];
                oacc[dt][0] = mfma16(av, pb0, oacc[dt][0]);
                oacc[dt][1] = mfma16(av, pb1, oacc[dt][1]);
            }
        }
    }

    // epilogue: O^T C-layout -> ctx[token][h*64+d], b64 packed stores
#pragma unroll
    for (int mt = 0; mt < 2; ++mt) {
        const float inv = 1.0f / l_r[mt];
        const int token = qt * 128 + w * 32 + mt * 16 + l15;
#pragma unroll
        for (int dt = 0; dt < 4; ++dt) {
            us4 o;
#pragma unroll
            for (int r = 0; r < 4; ++r) o[r] = f2bf(oacc[dt][mt][r] * inv);
            *(us4*)&ctx[(size_t)(b * SQL + token) * DM + h * HDM + dt * 16 + quad * 4] = o;
        }
    }
}

// ---------------- fused residual + LayerNorm (one wave per 512-elem row) -----------
template <bool WBF>
__global__ __launch_bounds__(256) void ln_fused(const float* __restrict__ xa,
                                                const float* __restrict__ xb,
                                                const float* __restrict__ g,
                                                const float* __restrict__ be,
                                                float* __restrict__ outf,
                                                u16t* __restrict__ outh) {
    const int row = blockIdx.x * 4 + (threadIdx.x >> 6);
    const int lane = threadIdx.x & 63;
    const size_t base = (size_t)row * DM;
    f32x4 a0 = *(const f32x4*)(xa + base + lane * 4);
    f32x4 b0 = *(const f32x4*)(xb + base + lane * 4);
    f32x4 a1 = *(const f32x4*)(xa + base + 256 + lane * 4);
    f32x4 b1 = *(const f32x4*)(xb + base + 256 + lane * 4);
    f32x4 v0 = a0 + b0, v1 = a1 + b1;
    float s = v0[0] + v0[1] + v0[2] + v0[3] + v1[0] + v1[1] + v1[2] + v1[3];
    float q = v0[0]*v0[0] + v0[1]*v0[1] + v0[2]*v0[2] + v0[3]*v0[3]
            + v1[0]*v1[0] + v1[1]*v1[1] + v1[2]*v1[2] + v1[3]*v1[3];
#pragma unroll
    for (int off = 1; off < 64; off <<= 1) {
        s += __shfl_xor(s, off);
        q += __shfl_xor(q, off);
    }
    const float mean = s * (1.0f / DM);
    const float var = q * (1.0f / DM) - mean * mean;
    const float rs = rsqrtf(var + 1e-5f);
    f32x4 g0 = *(const f32x4*)(g + lane * 4);
    f32x4 g1 = *(const f32x4*)(g + 256 + lane * 4);
    f32x4 e0 = *(const f32x4*)(be + lane * 4);
    f32x4 e1 = *(const f32x4*)(be + 256 + lane * 4);
    f32x4 y0, y1;
#pragma unroll
    for (int i = 0; i < 4; ++i) {
        y0[i] = (v0[i] - mean) * rs * g0[i] + e0[i];
        y1[i] = (v1[i] - mean) * rs * g1[i] + e1[i];
    }
    *(f32x4*)(outf + base + lane * 4) = y0;
    *(f32x4*)(outf + base + 256 + lane * 4) = y1;
    if (WBF) {
        us4 h0, h1;
#pragma unroll
        for (int i = 0; i < 4; ++i) { h0[i] = f2bf(y0[i]); h1[i] = f2bf(y1[i]); }
        *(us4*)(outh + base + lane * 4) = h0;
        *(us4*)(outh + base + 256 + lane * 4) = h1;
    }
}

// ---------------- host ----------------
extern "C" void kernel_launch(void* const* d_in, const int* in_sizes, int n_in,
                              void* d_out, int out_size, void* d_ws, size_t ws_size,
                              hipStream_t stream) {
    const float* src  = (const float*)d_in[0];
    const float* mask = (const float*)d_in[1];
    const float* Wq = (const float*)d_in[2];
    const float* bq = (const float*)d_in[3];
    const float* Wk = (const float*)d_in[4];
    const float* bk = (const float*)d_in[5];
    const float* Wv = (const float*)d_in[6];
    const float* bv = (const float*)d_in[7];
    const float* Wo = (const float*)d_in[8];
    const float* bo = (const float*)d_in[9];
    const float* W1 = (const float*)d_in[10];
    const float* b1 = (const float*)d_in[11];
    const float* W2 = (const float*)d_in[12];
    const float* b2 = (const float*)d_in[13];
    const float* ln1g = (const float*)d_in[14];
    const float* ln1b = (const float*)d_in[15];
    const float* ln2g = (const float*)d_in[16];
    const float* ln2b = (const float*)d_in[17];

    const int M = NB * SQL;  // 8192 tokens

    char* p = (char*)d_ws;
    auto take = [&](size_t bytes) {
        char* r = p;
        p += (bytes + 1023) & ~(size_t)1023;
        return r;
    };
    u16t* regA   = (u16t*)take((size_t)M * DFF * 2);      // qkv [M,1536] then h [M,2048]
    u16t* vtb    = (u16t*)take((size_t)NB * NHE * HDM * SQL * 2);
    u16t* ctxb   = (u16t*)take((size_t)M * DM * 2);
    float* sa_ff = (float*)take((size_t)M * DM * 4);      // sa then ff
    float* x1f   = (float*)take((size_t)M * DM * 4);
    u16t* x1h    = (u16t*)take((size_t)M * DM * 2);
    u16t* srcbf  = (u16t*)take((size_t)M * DM * 2);
    u16t* wqkv   = (u16t*)take((size_t)3 * DM * DM * 2);
    float* bqkv  = (float*)take((size_t)3 * DM * 4);
    u16t* woc    = (u16t*)take((size_t)DM * DM * 2);
    u16t* w1c    = (u16t*)take((size_t)DFF * DM * 2);
    u16t* w2c    = (u16t*)take((size_t)DM * DFF * 2);
    int* flag    = (int*)take(1024);
    u16t* qkvb   = regA;   // [M, 1536]
    u16t* hbuf   = regA;   // [M, 2048] (after flash is done with qkv)

    // all converts + bias pack + flag init in one launch
    convert_all<<<3585, 256, 0, stream>>>(src, Wq, Wk, Wv, Wo, W1, W2, bq, bk, bv,
                                          srcbf, wqkv, woc, w1c, w2c, bqkv, flag);
    // mask all-ones check (flag ordering guaranteed by stream)
    check_mask_k<<<4096, 256, 0, stream>>>((const f32x4*)mask, flag);

    // QKV projection: [8192,512] x [1536,512]^T -> [8192,1536] bf16
    gemm_bt<u16t, false><<<dim3(12, 64), 256, 0, stream>>>(srcbf, wqkv, bqkv, qkvb,
                                                           M, 3 * DM, DM, 3 * DM);
    // V transpose for flash A-operand
    transpose_v<<<dim3(SQL / 64, NHE, NB), 256, 0, stream>>>(qkvb, vtb);
    // attention
    flash_attn<<<dim3(SQL / 128, NHE, NB), 256, 0, stream>>>(qkvb, vtb, mask, flag, ctxb);
    // out projection -> sa (fp32)
    gemm_bt<float, false><<<dim3(4, 64), 256, 0, stream>>>(ctxb, woc, bo, sa_ff,
                                                           M, DM, DM, DM);
    // x1 = LN(src + sa)  (fp32 + bf16 copies)
    ln_fused<true><<<M / 4, 256, 0, stream>>>(src, sa_ff, ln1g, ln1b, x1f, x1h);
    // FFN1 + ReLU -> h (bf16)
    gemm_bt<u16t, true><<<dim3(16, 64), 256, 0, stream>>>(x1h, w1c, b1, hbuf,
                                                          M, DFF, DM, DFF);
    // FFN2 -> ff (fp32, reuses sa buffer)
    gemm_bt<float, false><<<dim3(4, 64), 256, 0, stream>>>(hbuf, w2c, b2, sa_ff,
                                                           M, DM, DFF, DM);
    // out = LN(x1 + ff)
    ln_fused<false><<<M / 4, 256, 0, stream>>>(x1f, sa_ff, ln2g, ln2b, (float*)d_out,
                                               (u16t*)nullptr);
}